// Round 1
// 329.956 us; speedup vs baseline: 1.0635x; 1.0635x over previous
//
#include <hip/hip_runtime.h>
#include <hip/hip_bf16.h>
#include <math.h>

typedef __bf16 bf16;
typedef __bf16 bf16x8 __attribute__((ext_vector_type(8)));
typedef __bf16 bf16x4 __attribute__((ext_vector_type(4)));
typedef float floatx4 __attribute__((ext_vector_type(4)));

#define B_ 2
#define T_ 2048
#define C_ 1024
#define H_ 16
#define HD_ 64

// Fragment-order layout for a GEMM operand X[R][Kd] (both A and B sides):
//   tile (rt = r>>4, kc = k>>5), tile base = (rt*(Kd>>5)+kc)*512 elements,
//   within tile: lane = (r&15) + 16*((k>>3)&3), elem = k&7  -> lane*8+elem.

// async global->LDS, 16B per lane; lds dest = uniform base + lane*16
__device__ __forceinline__ void gload_lds16(const bf16* g, bf16* l) {
    __builtin_amdgcn_global_load_lds(
        (const __attribute__((address_space(1))) unsigned int*)(g),
        (__attribute__((address_space(3))) unsigned int*)(l), 16, 0, 0);
}

// ---------------------------------------------------------------------------
// All weight preprocessing in ONE launch.
// ---------------------------------------------------------------------------
__global__ __launch_bounds__(256) void transpose_all(
        const float* __restrict__ w_in, const float* __restrict__ w_out,
        const float* __restrict__ w_fc, const float* __restrict__ w_proj,
        bf16* __restrict__ o_in, bf16* __restrict__ o_out,
        bf16* __restrict__ o_fc, bf16* __restrict__ o_proj) {
    __shared__ float shf[64 * 33];
    int t = blockIdx.x;
    int tid = threadIdx.x;
    if (t < 7168) {
        const float* src; bf16* dst; int K, N, idx;
        if (t < 3072) { src = w_in; dst = o_in; K = 1024; N = 3072; idx = t; }
        else          { src = w_fc; dst = o_fc; K = 1024; N = 4096; idx = t - 3072; }
        int ntx = N >> 5;
        int nt = (idx % ntx) * 32, kt = (idx / ntx) * 32;
        int tx = tid & 31, ty = tid >> 5;  // 32 x 8
        #pragma unroll
        for (int i = 0; i < 32; i += 8)
            shf[(ty + i) * 33 + tx] = src[(size_t)(kt + ty + i) * N + nt + tx];
        __syncthreads();
        #pragma unroll
        for (int i = 0; i < 32; i += 8)
            dst[(size_t)(nt + ty + i) * K + kt + tx] = (bf16)shf[tx * 33 + ty + i];
    } else {
        const float* src; bf16* dst; int K, idx;
        if (t < 7680) { src = w_out;  dst = o_out;  K = 1024; idx = t - 7168; }
        else          { src = w_proj; dst = o_proj; K = 4096; idx = t - 7680; }
        const int N = 1024;
        int n0 = (idx & 31) * 32, k0 = (idx >> 5) * 64;
        int col = tid & 31, kr = tid >> 5;
        #pragma unroll
        for (int s = 0; s < 8; s++)
            shf[(kr + s * 8) * 33 + col] = src[(size_t)(k0 + kr + s * 8) * N + n0 + col];
        __syncthreads();
        int tl = tid >> 6, l = tid & 63;
        int ntl = tl & 1, kcl = tl >> 1;
        int rr = ntl * 16 + (l & 15);
        int qd = l >> 4;
        bf16x8 v;
        #pragma unroll
        for (int e = 0; e < 8; e++)
            v[e] = (bf16)shf[(kcl * 32 + qd * 8 + e) * 33 + rr];
        size_t nt_g = (n0 >> 4) + ntl, kc_g = (k0 >> 5) + kcl;
        *(bf16x8*)(dst + (nt_g * (K >> 5) + kc_g) * 512 + l * 8) = v;
    }
}

// ---------------------------------------------------------------------------
// LayerNorm over C=1024. One block (256 threads) per row; 4 floats/thread.
// ---------------------------------------------------------------------------
__global__ __launch_bounds__(256) void ln_kernel(const float* __restrict__ x,
                                                 const float* __restrict__ g,
                                                 const float* __restrict__ b,
                                                 bf16* __restrict__ out_b,
                                                 float* __restrict__ out_f) {
    int row = blockIdx.x;
    int tid = threadIdx.x;
    const float* xr = x + (size_t)row * C_;
    float4 v = ((const float4*)xr)[tid];
    float s  = v.x + v.y + v.z + v.w;
    float ss = v.x * v.x + v.y * v.y + v.z * v.z + v.w * v.w;
    #pragma unroll
    for (int off = 32; off; off >>= 1) {
        s  += __shfl_down(s, off);
        ss += __shfl_down(ss, off);
    }
    __shared__ float red[8];
    int wid = tid >> 6;
    if ((tid & 63) == 0) { red[wid] = s; red[wid + 4] = ss; }
    __syncthreads();
    s  = red[0] + red[1] + red[2] + red[3];
    ss = red[4] + red[5] + red[6] + red[7];
    float mean = s * (1.0f / C_);
    float var  = ss * (1.0f / C_) - mean * mean;
    float rstd = rsqrtf(var + 1e-5f);
    float4 gv = ((const float4*)g)[tid];
    float4 bv = ((const float4*)b)[tid];
    float o0 = (v.x - mean) * rstd * gv.x + bv.x;
    float o1 = (v.y - mean) * rstd * gv.y + bv.y;
    float o2 = (v.z - mean) * rstd * gv.z + bv.z;
    float o3 = (v.w - mean) * rstd * gv.w + bv.w;
    bf16x4 ob = { (bf16)o0, (bf16)o1, (bf16)o2, (bf16)o3 };
    ((bf16x4*)out_b)[(size_t)row * 256 + tid] = ob;
    if (out_f) {
        float4 of; of.x = o0; of.y = o1; of.z = o2; of.w = o3;
        ((float4*)out_f)[(size_t)row * 256 + tid] = of;
    }
}

__device__ __forceinline__ float gelu_fast(float x) {
    // tanh-form GELU, |err| vs exact erf form < ~1e-3 (output slack ~0.10)
    float z2 = 1.5957691216f * (x + 0.044715f * x * x * x);   // 2*0.79788456*(x+..)
    float e = __expf(z2);
    float t = 1.0f - 2.0f * __builtin_amdgcn_rcpf(e + 1.0f);  // tanh(z)
    return 0.5f * x * (1.0f + t);
}

// ---------------------------------------------------------------------------
// 256x256-tile GEMM, 8 waves (2M x 4N), BK=64, 8-phase counted-vmcnt schedule
// (T2+T3+T4+T5). LDS 128 KB = 2 dbuf x (A[256][64] + B[256][64]).
// Per phase: {ds_read quadrant frags | issue 2 global_load_lds} -> barrier ->
// setprio(1) 16xMFMA setprio(0) -> [vmcnt(6) at phase 3/7] -> barrier.
// Stage "death schedule" (stage targets regions whose last reader finished a
// barrier earlier):
//   ph0: B(2i+1) rows128-255 -> Bs1 (dead since prev ph5)   [tail of buf1]
//   ph1: A(2i+2) rows0-63,128-191 -> As0 (qm0 read @ph0)
//   ph2: B(2i+2) rows0-127 -> Bs0       (read @ph0/ph1)
//   ph3: A(2i+2) rows64-127,192-255     (qm1 read @ph2)
//   ph4: B(2i+2) rows128-255 -> Bs0     (read @ph0/ph1)
//   ph5: A(2i+3) rows0-63,128-191 -> As1 (qm0 read @ph4)
//   ph6: B(2i+3) rows0-127 -> Bs1        (read @ph4/ph5)
//   ph7: A(2i+3) rows64-127,192-255      (qm1 read @ph6)
// vmcnt(6) before the ph3 barrier => everything except {ph1,ph2,ph3} stages
// has landed => buf1 (K-tile 2i+1) complete. vmcnt(6) before the ph7 barrier
// => buf0 (K-tile 2i+2) complete. Last iteration: vmcnt(0) at ph3.
// MODE 0: +bias, bf16 row-major out (qkv).
// MODE 1: +bias+gelu, FRAG-ORDER out via per-wave 64x68 LDS patches.
// ---------------------------------------------------------------------------
#define BAR() do { __builtin_amdgcn_sched_barrier(0); __builtin_amdgcn_s_barrier(); __builtin_amdgcn_sched_barrier(0); } while (0)
#define VMC6() asm volatile("s_waitcnt vmcnt(6)" ::: "memory")
#define VMC0() asm volatile("s_waitcnt vmcnt(0)" ::: "memory")

#define LOAD_A(AS, QM) \
  { _Pragma("unroll") for (int i_ = 0; i_ < 4; i_++) { \
      const int r_ = wm128 + ((QM) * 4 + i_) * 16 + lm; \
      _Pragma("unroll") for (int kc_ = 0; kc_ < 2; kc_++) \
        aR[i_][kc_] = *(const bf16x8*)((AS) + r_ * 64 + ((((kc_ << 2) | quad) ^ (lm & 7)) << 3)); } }

#define LOAD_B(BS, QN) \
  { _Pragma("unroll") for (int j_ = 0; j_ < 2; j_++) { \
      const int r_ = wn64 + ((QN) * 2 + j_) * 16 + lm; \
      _Pragma("unroll") for (int kc_ = 0; kc_ < 2; kc_++) \
        bR[QN][j_][kc_] = *(const bf16x8*)((BS) + r_ * 64 + ((((kc_ << 2) | quad) ^ (lm & 7)) << 3)); } }

#define MFMA_Q(QM, QN) \
  { __builtin_amdgcn_s_setprio(1); \
    _Pragma("unroll") for (int i_ = 0; i_ < 4; i_++) \
    _Pragma("unroll") for (int j_ = 0; j_ < 2; j_++) \
    _Pragma("unroll") for (int kc_ = 0; kc_ < 2; kc_++) \
      acc[(QM) * 4 + i_][(QN) * 2 + j_] = __builtin_amdgcn_mfma_f32_16x16x32_bf16( \
          aR[i_][kc_], bR[QN][j_][kc_], acc[(QM) * 4 + i_][(QN) * 2 + j_], 0, 0, 0); \
    __builtin_amdgcn_s_setprio(0); }

#define STG(gb, lb, r0v, k0v) \
    gload_lds16((gb) + (size_t)((r0v) + sr8) * K + (k0v) + scb, (lb) + ((r0v) + wid * 8) * 64)

template<int MODE>
__global__ __launch_bounds__(512, 2) void gemm256(const bf16* __restrict__ A,
                                                  const bf16* __restrict__ Bt,
                                                  const float* __restrict__ bias,
                                                  void* __restrict__ out,
                                                  int M, int N, int K) {
    (void)M;
    __shared__ __align__(16) bf16 smem[4 * 256 * 64];   // 128 KB
    bf16* As0 = smem;
    bf16* Bs0 = smem + 1 * 256 * 64;
    bf16* As1 = smem + 2 * 256 * 64;
    bf16* Bs1 = smem + 3 * 256 * 64;

    // XCD-chunked bijective swizzle (gridDim.x % 8 == 0 for all our shapes)
    int ntn = N >> 8;
    int lin = blockIdx.x;
    int id  = (lin & 7) * (gridDim.x >> 3) + (lin >> 3);
    int mt = id / ntn, nt = id - mt * ntn;
    int m0 = mt << 8, n0 = nt << 8;

    int tid = threadIdx.x;
    int wid = __builtin_amdgcn_readfirstlane(tid >> 6);
    int lane = tid & 63;
    int lm = lane & 15, quad = lane >> 4;
    int wm128 = (wid & 1) * 128;     // wave M offset within tile
    int wn64  = (wid >> 1) * 64;     // wave N offset within tile

    const bf16* Ablk = A  + (size_t)m0 * K;
    const bf16* Bblk = Bt + (size_t)n0 * K;

    int sr8 = wid * 8 + (lane >> 3);               // staging row within round
    int scb = ((lane & 7) ^ (lane >> 3)) << 3;     // xor-swizzled source col

    floatx4 acc[8][4];
    #pragma unroll
    for (int f = 0; f < 8; f++)
        #pragma unroll
        for (int g = 0; g < 4; g++) { floatx4 z = {0.f, 0.f, 0.f, 0.f}; acc[f][g] = z; }
    bf16x8 aR[4][2], bR[2][2][2];

    int nI = K >> 7;   // iterations; 2 K-tiles (BK=64) each

    // prologue: K-tile 0 full (8 loads, oldest), K-tile 1 minus B rows128-255
    STG(Ablk, As0, 0, 0);   STG(Ablk, As0, 64, 0);
    STG(Ablk, As0, 128, 0); STG(Ablk, As0, 192, 0);
    STG(Bblk, Bs0, 0, 0);   STG(Bblk, Bs0, 64, 0);
    STG(Bblk, Bs0, 128, 0); STG(Bblk, Bs0, 192, 0);
    STG(Ablk, As1, 0, 64);  STG(Ablk, As1, 128, 64);
    STG(Bblk, Bs1, 0, 64);  STG(Bblk, Bs1, 64, 64);
    STG(Ablk, As1, 64, 64); STG(Ablk, As1, 192, 64);
    VMC6();                 // K-tile 0 landed; <=6 (K-tile 1 partial) in flight
    BAR();

    for (int it = 0; it < nI; it++) {
        int kE = (2 * it + 2) << 6;
        int kO = (2 * it + 3) << 6;
        int kT = (2 * it + 1) << 6;
        bool nl = (it + 1 < nI);
        // phase 0
        LOAD_A(As0, 0); LOAD_B(Bs0, 0);
        STG(Bblk, Bs1, 128, kT); STG(Bblk, Bs1, 192, kT);
        BAR(); MFMA_Q(0, 0); BAR();
        // phase 1
        LOAD_B(Bs0, 1);
        if (nl) { STG(Ablk, As0, 0, kE); STG(Ablk, As0, 128, kE); }
        BAR(); MFMA_Q(0, 1); BAR();
        // phase 2
        LOAD_A(As0, 1);
        if (nl) { STG(Bblk, Bs0, 0, kE); STG(Bblk, Bs0, 64, kE); }
        BAR(); MFMA_Q(1, 0); BAR();
        // phase 3
        if (nl) { STG(Ablk, As0, 64, kE); STG(Ablk, As0, 192, kE); }
        BAR(); MFMA_Q(1, 1);
        if (nl) { VMC6(); } else { VMC0(); }   // buf1 (K-tile 2it+1) ready
        BAR();
        // phase 4
        LOAD_A(As1, 0); LOAD_B(Bs1, 0);
        if (nl) { STG(Bblk, Bs0, 128, kE); STG(Bblk, Bs0, 192, kE); }
        BAR(); MFMA_Q(0, 0); BAR();
        // phase 5
        LOAD_B(Bs1, 1);
        if (nl) { STG(Ablk, As1, 0, kO); STG(Ablk, As1, 128, kO); }
        BAR(); MFMA_Q(0, 1); BAR();
        // phase 6
        LOAD_A(As1, 1);
        if (nl) { STG(Bblk, Bs1, 0, kO); STG(Bblk, Bs1, 64, kO); }
        BAR(); MFMA_Q(1, 0); BAR();
        // phase 7
        if (nl) { STG(Ablk, As1, 64, kO); STG(Ablk, As1, 192, kO); }
        BAR(); MFMA_Q(1, 1);
        if (nl) { VMC6(); }                    // buf0 (K-tile 2it+2) ready
        BAR();
    }

    if (MODE == 0) {
        bf16* ob = (bf16*)out;
        #pragma unroll
        for (int f = 0; f < 8; f++) {
            int row0 = m0 + wm128 + f * 16 + quad * 4;
            #pragma unroll
            for (int g = 0; g < 4; g++) {
                int n = n0 + wn64 + g * 16 + lm;
                float bsn = bias[n];
                #pragma unroll
                for (int r = 0; r < 4; r++)
                    ob[(size_t)(row0 + r) * N + n] = (bf16)(acc[f][g][r] + bsn);
            }
        }
    } else {
        // frag-order out via per-wave 64x68 patch (no cross-wave sharing, no
        // barriers needed; 8 waves x 8.7 KB = 69.6 KB inside smem)
        bf16* ob = (bf16*)out;
        bf16* patch = smem + wid * (64 * 68);
        size_t mtb = (size_t)((m0 + wm128) >> 4);
        int ncb = (n0 + wn64) >> 5;
        #pragma unroll
        for (int h = 0; h < 2; h++) {
            #pragma unroll
            for (int ff = 0; ff < 4; ff++)
                #pragma unroll
                for (int g = 0; g < 4; g++) {
                    int n = n0 + wn64 + g * 16 + lm;
                    float bsn = bias[n];
                    #pragma unroll
                    for (int r = 0; r < 4; r++)
                        patch[(ff * 16 + quad * 4 + r) * 68 + g * 16 + lm] =
                            (bf16)gelu_fast(acc[h * 4 + ff][g][r] + bsn);
                }
            #pragma unroll
            for (int ff = 0; ff < 4; ff++)
                #pragma unroll
                for (int kc = 0; kc < 2; kc++) {
                    bf16x8 v = *(const bf16x8*)&patch[(ff * 16 + lm) * 68 + kc * 32 + quad * 8];
                    size_t tile = (mtb + h * 4 + ff) * (size_t)(N >> 5) + ncb + kc;
                    *(bf16x8*)(ob + tile * 512 + lane * 8) = v;
                }
        }
    }
}

// ---------------------------------------------------------------------------
// Narrow-N GEMM, fully LDS-free: both operands in frag order, direct
// global->register loads, 3-buffer rotation = prefetch distance 2 (doubles
// latency coverage vs the old double-buffer), NO barriers.
// 128x64 block tile, 4 waves (64x32 each). XCD-swizzled 1D grid.
// ---------------------------------------------------------------------------
#define GD_STEP(BUF, SS) \
  if ((SS) < S) { \
    int kp_ = 2 * (SS) + 4; \
    if (kp_ < KC) { \
      _Pragma("unroll") for (int i_ = 0; i_ < 4; i_++) \
        _Pragma("unroll") for (int c_ = 0; c_ < 2; c_++) \
          ab[((BUF) + 2) % 3][i_][c_] = *(const bf16x8*)(Ab + ((size_t)i_ * KC + kp_ + c_) * 512); \
      _Pragma("unroll") for (int j_ = 0; j_ < 2; j_++) \
        _Pragma("unroll") for (int c_ = 0; c_ < 2; c_++) \
          bb[((BUF) + 2) % 3][j_][c_] = *(const bf16x8*)(Bb + ((size_t)j_ * KC + kp_ + c_) * 512); \
    } \
    _Pragma("unroll") for (int c_ = 0; c_ < 2; c_++) \
      _Pragma("unroll") for (int i_ = 0; i_ < 4; i_++) \
        _Pragma("unroll") for (int j_ = 0; j_ < 2; j_++) \
          acc[i_][j_] = __builtin_amdgcn_mfma_f32_16x16x32_bf16(ab[BUF][i_][c_], bb[BUF][j_][c_], acc[i_][j_], 0, 0, 0); \
  }

__global__ __launch_bounds__(256, 2) void gemm_direct(const bf16* __restrict__ Af,
                                                      const bf16* __restrict__ Bf,
                                                      const float* __restrict__ bias,
                                                      const float* __restrict__ add,
                                                      float* __restrict__ out,
                                                      int M, int N, int K) {
    (void)M;
    int lin = blockIdx.x;
    int xcd = lin & 7, loc = lin >> 3;
    int m0 = ((xcd << 2) | (loc & 3)) * 128;
    int n0 = (loc >> 2) * 64;
    int tid = threadIdx.x;
    int wid = __builtin_amdgcn_readfirstlane(tid >> 6);
    int lane = tid & 63;
    int lm = lane & 15, quad = lane >> 4;
    int wm = (wid & 1) * 64, wn = (wid >> 1) * 32;
    int KC = K >> 5;
    const bf16* Ab = Af + ((size_t)((m0 + wm) >> 4) * KC) * 512 + lane * 8;
    const bf16* Bb = Bf + ((size_t)((n0 + wn) >> 4) * KC) * 512 + lane * 8;

    floatx4 acc[4][2];
    #pragma unroll
    for (int i = 0; i < 4; i++)
        #pragma unroll
        for (int j = 0; j < 2; j++) { floatx4 z = {0.f, 0.f, 0.f, 0.f}; acc[i][j] = z; }

    bf16x8 ab[3][4][2], bb[3][2][2];
    #pragma unroll
    for (int c = 0; c < 2; c++) {
        #pragma unroll
        for (int i = 0; i < 4; i++) {
            ab[0][i][c] = *(const bf16x8*)(Ab + ((size_t)i * KC + c) * 512);
            ab[1][i][c] = *(const bf16x8*)(Ab + ((size_t)i * KC + 2 + c) * 512);
        }
        #pragma unroll
        for (int j = 0; j < 2; j++) {
            bb[0][j][c] = *(const bf16x8*)(Bb + ((size_t)j * KC + c) * 512);
            bb[1][j][c] = *(const bf16x8*)(Bb + ((size_t)j * KC + 2 + c) * 512);
        }
    }

    int S = KC >> 1;   // steps of 2 k-chunks; step s consumes buf[s%3]
    for (int s0 = 0; s0 < S; s0 += 3) {
        GD_STEP(0, s0);
        GD_STEP(1, s0 + 1);
        GD_STEP(2, s0 + 2);
    }

    #pragma unroll
    for (int i = 0; i < 4; i++)
        #pragma unroll
        for (int j = 0; j < 2; j++) {
            int mbase = m0 + wm + i * 16 + quad * 4;
            int n     = n0 + wn + j * 16 + lm;
            float bsn = bias[n];
            #pragma unroll
            for (int r = 0; r < 4; r++) {
                size_t idx = (size_t)(mbase + r) * N + n;
                out[idx] = acc[i][j][r] + bsn + add[idx];
            }
        }
}

// ---------------------------------------------------------------------------
// Flash attention, MFMA, S^T formulation — 8 waves x 16 q-rows (512 thr).
// Q pre-scaled by 1/sqrt(64); wave-uniform diagonal-tile branch.
// Output in FRAG ORDER for gemm_direct.
// ---------------------------------------------------------------------------
#define QT_ 128
#define KT_ 64

__global__ __launch_bounds__(512) void attn_mfma_kernel(const bf16* __restrict__ qkv,
                                                        bf16* __restrict__ of) {
    int bh = blockIdx.x;
    int b = bh >> 4, h = bh & 15;
    int q0 = (gridDim.y - 1 - blockIdx.y) * QT_;   // heavy-first
    int tid = threadIdx.x, wid = tid >> 6, lane = tid & 63;
    int lm = lane & 15, quad = lane >> 4;
    int sw = lm & 7;
    int r0 = q0 + wid * 16;                        // this wave's 16 q-rows

    const bf16* base = qkv + (size_t)b * T_ * (3 * C_) + h * (3 * HD_);

    __shared__ __align__(16) bf16 Ks[KT_][72];      // K rows [key][d]
    __shared__ __align__(16) bf16 Vt[HD_][72];      // V^T [d][key-swizzled]
    __shared__ __align__(16) bf16 PsT[8][16][64];   // per-wave P [qrow][key-swizzled]

    bf16x8 qf[2];
    #pragma unroll
    for (int kc = 0; kc < 2; kc++) {
        bf16x8 t = *(const bf16x8*)(base + (size_t)(r0 + lm) * (3 * C_) + kc * 32 + quad * 8);
        #pragma unroll
        for (int e = 0; e < 8; e++) t[e] = (bf16)((float)t[e] * 0.125f);
        qf[kc] = t;
    }

    floatx4 acc_o[4];
    #pragma unroll
    for (int dn = 0; dn < 4; dn++) { floatx4 z = {0.f, 0.f, 0.f, 0.f}; acc_o[dn] = z; }
    float mst = -1e30f, lst = 0.0f;

    int srow = tid >> 3;              // 0..63
    int scol = (tid & 7) * 8;

    int kmax = q0 + QT_;
    for (int k0 = 0; k0 < kmax; k0 += KT_) {
        bf16x8 kv = *(const bf16x8*)(base + (size_t)(k0 + srow) * (3 * C_) + HD_ + scol);
        bf16x8 vv = *(const bf16x8*)(base + (size_t)(k0 + srow) * (3 * C_) + 2 * HD_ + scol);
        __syncthreads();
        *(bf16x8*)(&Ks[srow][scol]) = kv;
        {
            int c = scol >> 3;
            int pk = ((srow >> 3) ^ c) * 8 + (srow & 7);
            #pragma unroll
            for (int j = 0; j < 8; j++) Vt[scol + j][pk] = vv[j];
        }
        __syncthreads();

        if (k0 <= r0 + 15) {
            floatx4 st[4];
            #pragma unroll
            for (int bn = 0; bn < 4; bn++) { floatx4 z = {0.f, 0.f, 0.f, 0.f}; st[bn] = z; }
            #pragma unroll
            for (int kc = 0; kc < 2; kc++) {
                bf16x8 kf[4];
                #pragma unroll
                for (int bn = 0; bn < 4; bn++)
                    kf[bn] = *(const bf16x8*)(&Ks[bn * 16 + lm][kc * 32 + quad * 8]);
                #pragma unroll
                for (int bn = 0; bn < 4; bn++)
                    st[bn] = __builtin_amdgcn_mfma_f32_16x16x32_bf16(kf[bn], qf[kc], st[bn], 0, 0, 0);
            }

            float vv_[4][4];
            float rm = -1e30f;
            if (k0 + KT_ - 1 > r0) {      // diagonal tile (wave-uniform branch)
                int gq = r0 + lm;
                #pragma unroll
                for (int bn = 0; bn < 4; bn++)
                    #pragma unroll
                    for (int r = 0; r < 4; r++) {
                        int key = k0 + bn * 16 + quad * 4 + r;
                        float sv = (key <= gq) ? st[bn][r] : -1e30f;
                        vv_[bn][r] = sv;
                        rm = fmaxf(rm, sv);
                    }
            } else {
                #pragma unroll
                for (int bn = 0; bn < 4; bn++)
                    #pragma unroll
                    for (int r = 0; r < 4; r++) {
                        vv_[bn][r] = st[bn][r];
                        rm = fmaxf(rm, st[bn][r]);
                    }
            }
            rm = fmaxf(rm, __shfl_xor(rm, 16));
            rm = fmaxf(rm, __shfl_xor(rm, 32));
            float mnew = fmaxf(mst, rm);
            float alpha = __expf(mst - mnew);
            mst = mnew;
            float ps = 0.f;
            #pragma unroll
            for (int bn = 0; bn < 4; bn++) {
                float p0 = __expf(vv_[bn][0] - mnew);
                float p1 = __expf(vv_[bn][1] - mnew);
                float p2 = __expf(vv_[bn][2] - mnew);
                float p3 = __expf(vv_[bn][3] - mnew);
                ps += (p0 + p1) + (p2 + p3);
                bf16x4 pk = { (bf16)p0, (bf16)p1, (bf16)p2, (bf16)p3 };
                int kb = bn * 2 + (quad >> 1);
                int col = ((kb ^ sw) << 3) + (quad & 1) * 4;
                *(bf16x4*)(&PsT[wid][lm][col]) = pk;
            }
            ps += __shfl_xor(ps, 16);
            ps += __shfl_xor(ps, 32);
            lst = lst * alpha + ps;

            #pragma unroll
            for (int r = 0; r < 4; r++) {
                float ar = __shfl(alpha, quad * 4 + r);
                #pragma unroll
                for (int dn = 0; dn < 4; dn++) acc_o[dn][r] *= ar;
            }

            __asm__ volatile("s_waitcnt lgkmcnt(0)" ::: "memory");

            #pragma unroll
            for (int kc = 0; kc < 2; kc++) {
                bf16x8 pa = *(const bf16x8*)(&PsT[wid][lm][((kc * 4 + quad) ^ sw) << 3]);
                bf16x8 vfr[4];
                #pragma unroll
                for (int dn = 0; dn < 4; dn++) {
                    int d = dn * 16 + lm;
                    int swd = (d >> 3) & 7;
                    vfr[dn] = *(const bf16x8*)(&Vt[d][(((kc * 4 + quad) ^ swd) << 3)]);
                }
                #pragma unroll
                for (int dn = 0; dn < 4; dn++)
                    acc_o[dn] = __builtin_amdgcn_mfma_f32_16x16x32_bf16(pa, vfr[dn], acc_o[dn], 0, 0, 0);
            }
        }
    }

    float il = 1.0f / lst;
    #pragma unroll
    for (int r = 0; r < 4; r++) {
        float ir = __shfl(il, quad * 4 + r);
        #pragma unroll
        for (int dn = 0; dn < 4; dn++)
            PsT[wid][quad * 4 + r][dn * 16 + lm] = (bf16)(acc_o[dn][r] * ir);
    }
    __asm__ volatile("s_waitcnt lgkmcnt(0)" ::: "memory");
    size_t mtb = ((size_t)b * T_ + r0) >> 4;
    #pragma unroll
    for (int kcl = 0; kcl < 2; kcl++) {
        bf16x8 v = *(const bf16x8*)&PsT[wid][lm][kcl * 32 + quad * 8];
        *(bf16x8*)(of + (mtb * (C_ >> 5) + (h * 2 + kcl)) * 512 + lane * 8) = v;
    }
}

// ---------------------------------------------------------------------------
extern "C" void kernel_launch(void* const* d_in, const int* in_sizes, int n_in,
                              void* d_out, int out_size, void* d_ws, size_t ws_size,
                              hipStream_t stream) {
    (void)in_sizes; (void)n_in; (void)out_size; (void)ws_size;
    const float* x      = (const float*)d_in[0];
    const float* ln1_g  = (const float*)d_in[1];
    const float* ln1_b  = (const float*)d_in[2];
    const float* ln2_g  = (const float*)d_in[3];
    const float* ln2_b  = (const float*)d_in[4];
    const float* w_in   = (const float*)d_in[5];
    const float* b_in   = (const float*)d_in[6];
    const float* w_out  = (const float*)d_in[7];
    const float* b_out  = (const float*)d_in[8];
    const float* w_fc   = (const float*)d_in[9];
    const float* b_fc   = (const float*)d_in[10];
    const float* w_proj = (const float*)d_in[11];
    const float* b_proj = (const float*)d_in[12];

    char* ws = (char*)d_ws;
    const size_t MB = 1024 * 1024;
    bf16*  w_inT   = (bf16*)(ws + 0);        // 6 MB row-major (N,K)
    bf16*  w_outF  = (bf16*)(ws + 6 * MB);   // 2 MB frag
    bf16*  w_fcT   = (bf16*)(ws + 8 * MB);   // 8 MB row-major (N,K)
    bf16*  w_projF = (bf16*)(ws + 16 * MB);  // 8 MB frag
    bf16*  qkv     = (bf16*)(ws + 24 * MB);  // 24 MB (shares 32MB region with fc_frag)
    bf16*  fc_frag = (bf16*)(ws + 24 * MB);  // 32 MB frag
    bf16*  o_frag  = (bf16*)(ws + 56 * MB);  // 8 MB frag (shares with y_b)
    bf16*  y_b     = (bf16*)(ws + 56 * MB);  // 8 MB
    bf16*  h_b     = (bf16*)(ws + 64 * MB);  // 8 MB (shares 16MB region with x1)
    float* x1      = (float*)(ws + 64 * MB); // 16 MB
    float* y_f     = (float*)(ws + 80 * MB); // 16 MB

    const int M = B_ * T_;  // 4096

    transpose_all<<<9728, 256, 0, stream>>>(w_in, w_out, w_fc, w_proj,
                                            w_inT, w_outF, w_fcT, w_projF);

    ln_kernel<<<M, 256, 0, stream>>>(x, ln1_g, ln1_b, h_b, nullptr);
    gemm256<0><<<(M >> 8) * ((3 * C_) >> 8), 512, 0, stream>>>(h_b, w_inT, b_in,
                                                               qkv, M, 3 * C_, C_);
    attn_mfma_kernel<<<dim3(B_ * H_, T_ / QT_), 512, 0, stream>>>(qkv, o_frag);
    gemm_direct<<<512, 256, 0, stream>>>(o_frag, w_outF, b_out, x, x1, M, C_, C_);
    ln_kernel<<<M, 256, 0, stream>>>(x1, ln2_g, ln2_b, y_b, y_f);
    gemm256<1><<<(M >> 8) * ((4 * C_) >> 8), 512, 0, stream>>>(y_b, w_fcT, b_fc,
                                                               fc_frag, M, 4 * C_, C_);
    gemm_direct<<<512, 256, 0, stream>>>(fc_frag, w_projF, b_proj, y_f,
                                         (float*)d_out, M, C_, 4 * C_);
}

// Round 2
// 319.638 us; speedup vs baseline: 1.0979x; 1.0323x over previous
//
#include <hip/hip_runtime.h>
#include <hip/hip_bf16.h>
#include <math.h>

typedef __bf16 bf16;
typedef __bf16 bf16x8 __attribute__((ext_vector_type(8)));
typedef __bf16 bf16x4 __attribute__((ext_vector_type(4)));
typedef float floatx4 __attribute__((ext_vector_type(4)));

#define B_ 2
#define T_ 2048
#define C_ 1024
#define H_ 16
#define HD_ 64

// async global->LDS, 16B per lane; lds dest = uniform base + lane*16
__device__ __forceinline__ void gload_lds16(const bf16* g, bf16* l) {
    __builtin_amdgcn_global_load_lds(
        (const __attribute__((address_space(1))) unsigned int*)(g),
        (__attribute__((address_space(3))) unsigned int*)(l), 16, 0, 0);
}

// ---------------------------------------------------------------------------
// Weight preprocessing: all four weights (K,N) f32 -> (N,K) bf16 row-major.
// 32x32 tiles, 256 threads (32x8).
// ---------------------------------------------------------------------------
__global__ __launch_bounds__(256) void transpose_all(
        const float* __restrict__ w_in, const float* __restrict__ w_out,
        const float* __restrict__ w_fc, const float* __restrict__ w_proj,
        bf16* __restrict__ o_in, bf16* __restrict__ o_out,
        bf16* __restrict__ o_fc, bf16* __restrict__ o_proj) {
    __shared__ float shf[32 * 33];
    int t = blockIdx.x;
    int tid = threadIdx.x;
    const float* src; bf16* dst; int K, N, idx;
    if (t < 3072)      { src = w_in;   dst = o_in;   K = 1024; N = 3072; idx = t; }
    else if (t < 7168) { src = w_fc;   dst = o_fc;   K = 1024; N = 4096; idx = t - 3072; }
    else if (t < 8192) { src = w_out;  dst = o_out;  K = 1024; N = 1024; idx = t - 7168; }
    else               { src = w_proj; dst = o_proj; K = 4096; N = 1024; idx = t - 8192; }
    int ntx = N >> 5;
    int nt = (idx % ntx) * 32, kt = (idx / ntx) * 32;
    int tx = tid & 31, ty = tid >> 5;  // 32 x 8
    #pragma unroll
    for (int i = 0; i < 32; i += 8)
        shf[(ty + i) * 33 + tx] = src[(size_t)(kt + ty + i) * N + nt + tx];
    __syncthreads();
    #pragma unroll
    for (int i = 0; i < 32; i += 8)
        dst[(size_t)(nt + ty + i) * K + kt + tx] = (bf16)shf[tx * 33 + ty + i];
}

// ---------------------------------------------------------------------------
// LayerNorm over C=1024. One block (256 threads) per row; 4 floats/thread.
// ---------------------------------------------------------------------------
__global__ __launch_bounds__(256) void ln_kernel(const float* __restrict__ x,
                                                 const float* __restrict__ g,
                                                 const float* __restrict__ b,
                                                 bf16* __restrict__ out_b,
                                                 float* __restrict__ out_f) {
    int row = blockIdx.x;
    int tid = threadIdx.x;
    const float* xr = x + (size_t)row * C_;
    float4 v = ((const float4*)xr)[tid];
    float s  = v.x + v.y + v.z + v.w;
    float ss = v.x * v.x + v.y * v.y + v.z * v.z + v.w * v.w;
    #pragma unroll
    for (int off = 32; off; off >>= 1) {
        s  += __shfl_down(s, off);
        ss += __shfl_down(ss, off);
    }
    __shared__ float red[8];
    int wid = tid >> 6;
    if ((tid & 63) == 0) { red[wid] = s; red[wid + 4] = ss; }
    __syncthreads();
    s  = red[0] + red[1] + red[2] + red[3];
    ss = red[4] + red[5] + red[6] + red[7];
    float mean = s * (1.0f / C_);
    float var  = ss * (1.0f / C_) - mean * mean;
    float rstd = rsqrtf(var + 1e-5f);
    float4 gv = ((const float4*)g)[tid];
    float4 bv = ((const float4*)b)[tid];
    float o0 = (v.x - mean) * rstd * gv.x + bv.x;
    float o1 = (v.y - mean) * rstd * gv.y + bv.y;
    float o2 = (v.z - mean) * rstd * gv.z + bv.z;
    float o3 = (v.w - mean) * rstd * gv.w + bv.w;
    bf16x4 ob = { (bf16)o0, (bf16)o1, (bf16)o2, (bf16)o3 };
    ((bf16x4*)out_b)[(size_t)row * 256 + tid] = ob;
    if (out_f) {
        float4 of; of.x = o0; of.y = o1; of.z = o2; of.w = o3;
        ((float4*)out_f)[(size_t)row * 256 + tid] = of;
    }
}

__device__ __forceinline__ float gelu_fast(float x) {
    // tanh-form GELU, |err| vs exact erf form < ~1e-3 (output slack ~0.10)
    float z2 = 1.5957691216f * (x + 0.044715f * x * x * x);   // 2*0.79788456*(x+..)
    float e = __expf(z2);
    float t = 1.0f - 2.0f * __builtin_amdgcn_rcpf(e + 1.0f);  // tanh(z)
    return 0.5f * x * (1.0f + t);
}

// ---------------------------------------------------------------------------
// 256x256-tile GEMM, 8 waves (2M x 4N), BK=64, 8-phase counted-vmcnt schedule
// (T2+T3+T4+T5). LDS 128 KB = 2 dbuf x (A[256][64] + B[256][64]).
// MODE 0: +bias, bf16 row-major out (qkv).
// MODE 1: +bias+gelu, bf16 ROW-MAJOR out via per-wave 64x68 LDS patches.
// ---------------------------------------------------------------------------
#define BAR() do { __builtin_amdgcn_sched_barrier(0); __builtin_amdgcn_s_barrier(); __builtin_amdgcn_sched_barrier(0); } while (0)
#define VMC6() asm volatile("s_waitcnt vmcnt(6)" ::: "memory")
#define VMC0() asm volatile("s_waitcnt vmcnt(0)" ::: "memory")

#define LOAD_A(AS, QM) \
  { _Pragma("unroll") for (int i_ = 0; i_ < 4; i_++) { \
      const int r_ = wm128 + ((QM) * 4 + i_) * 16 + lm; \
      _Pragma("unroll") for (int kc_ = 0; kc_ < 2; kc_++) \
        aR[i_][kc_] = *(const bf16x8*)((AS) + r_ * 64 + ((((kc_ << 2) | quad) ^ (lm & 7)) << 3)); } }

#define LOAD_B(BS, QN) \
  { _Pragma("unroll") for (int j_ = 0; j_ < 2; j_++) { \
      const int r_ = wn64 + ((QN) * 2 + j_) * 16 + lm; \
      _Pragma("unroll") for (int kc_ = 0; kc_ < 2; kc_++) \
        bR[QN][j_][kc_] = *(const bf16x8*)((BS) + r_ * 64 + ((((kc_ << 2) | quad) ^ (lm & 7)) << 3)); } }

#define MFMA_Q(QM, QN) \
  { __builtin_amdgcn_s_setprio(1); \
    _Pragma("unroll") for (int i_ = 0; i_ < 4; i_++) \
    _Pragma("unroll") for (int j_ = 0; j_ < 2; j_++) \
    _Pragma("unroll") for (int kc_ = 0; kc_ < 2; kc_++) \
      acc[(QM) * 4 + i_][(QN) * 2 + j_] = __builtin_amdgcn_mfma_f32_16x16x32_bf16( \
          aR[i_][kc_], bR[QN][j_][kc_], acc[(QM) * 4 + i_][(QN) * 2 + j_], 0, 0, 0); \
    __builtin_amdgcn_s_setprio(0); }

#define STG(gb, lb, r0v, k0v) \
    gload_lds16((gb) + (size_t)((r0v) + sr8) * K + (k0v) + scb, (lb) + ((r0v) + wid * 8) * 64)

template<int MODE>
__global__ __launch_bounds__(512, 2) void gemm256(const bf16* __restrict__ A,
                                                  const bf16* __restrict__ Bt,
                                                  const float* __restrict__ bias,
                                                  void* __restrict__ out,
                                                  int M, int N, int K) {
    (void)M;
    __shared__ __align__(16) bf16 smem[4 * 256 * 64];   // 128 KB
    bf16* As0 = smem;
    bf16* Bs0 = smem + 1 * 256 * 64;
    bf16* As1 = smem + 2 * 256 * 64;
    bf16* Bs1 = smem + 3 * 256 * 64;

    // XCD-chunked bijective swizzle (gridDim.x % 8 == 0 for all our shapes)
    int ntn = N >> 8;
    int lin = blockIdx.x;
    int id  = (lin & 7) * (gridDim.x >> 3) + (lin >> 3);
    int mt = id / ntn, nt = id - mt * ntn;
    int m0 = mt << 8, n0 = nt << 8;

    int tid = threadIdx.x;
    int wid = __builtin_amdgcn_readfirstlane(tid >> 6);
    int lane = tid & 63;
    int lm = lane & 15, quad = lane >> 4;
    int wm128 = (wid & 1) * 128;     // wave M offset within tile
    int wn64  = (wid >> 1) * 64;     // wave N offset within tile

    const bf16* Ablk = A  + (size_t)m0 * K;
    const bf16* Bblk = Bt + (size_t)n0 * K;

    int sr8 = wid * 8 + (lane >> 3);               // staging row within round
    int scb = ((lane & 7) ^ (lane >> 3)) << 3;     // xor-swizzled source col

    floatx4 acc[8][4];
    #pragma unroll
    for (int f = 0; f < 8; f++)
        #pragma unroll
        for (int g = 0; g < 4; g++) { floatx4 z = {0.f, 0.f, 0.f, 0.f}; acc[f][g] = z; }
    bf16x8 aR[4][2], bR[2][2][2];

    int nI = K >> 7;   // iterations; 2 K-tiles (BK=64) each

    // prologue: K-tile 0 full (8 loads, oldest), K-tile 1 minus B rows128-255
    STG(Ablk, As0, 0, 0);   STG(Ablk, As0, 64, 0);
    STG(Ablk, As0, 128, 0); STG(Ablk, As0, 192, 0);
    STG(Bblk, Bs0, 0, 0);   STG(Bblk, Bs0, 64, 0);
    STG(Bblk, Bs0, 128, 0); STG(Bblk, Bs0, 192, 0);
    STG(Ablk, As1, 0, 64);  STG(Ablk, As1, 128, 64);
    STG(Bblk, Bs1, 0, 64);  STG(Bblk, Bs1, 64, 64);
    STG(Ablk, As1, 64, 64); STG(Ablk, As1, 192, 64);
    VMC6();                 // K-tile 0 landed; <=6 (K-tile 1 partial) in flight
    BAR();

    for (int it = 0; it < nI; it++) {
        int kE = (2 * it + 2) << 6;
        int kO = (2 * it + 3) << 6;
        int kT = (2 * it + 1) << 6;
        bool nl = (it + 1 < nI);
        // phase 0
        LOAD_A(As0, 0); LOAD_B(Bs0, 0);
        STG(Bblk, Bs1, 128, kT); STG(Bblk, Bs1, 192, kT);
        BAR(); MFMA_Q(0, 0); BAR();
        // phase 1
        LOAD_B(Bs0, 1);
        if (nl) { STG(Ablk, As0, 0, kE); STG(Ablk, As0, 128, kE); }
        BAR(); MFMA_Q(0, 1); BAR();
        // phase 2
        LOAD_A(As0, 1);
        if (nl) { STG(Bblk, Bs0, 0, kE); STG(Bblk, Bs0, 64, kE); }
        BAR(); MFMA_Q(1, 0); BAR();
        // phase 3
        if (nl) { STG(Ablk, As0, 64, kE); STG(Ablk, As0, 192, kE); }
        BAR(); MFMA_Q(1, 1);
        if (nl) { VMC6(); } else { VMC0(); }   // buf1 (K-tile 2it+1) ready
        BAR();
        // phase 4
        LOAD_A(As1, 0); LOAD_B(Bs1, 0);
        if (nl) { STG(Bblk, Bs0, 128, kE); STG(Bblk, Bs0, 192, kE); }
        BAR(); MFMA_Q(0, 0); BAR();
        // phase 5
        LOAD_B(Bs1, 1);
        if (nl) { STG(Ablk, As1, 0, kO); STG(Ablk, As1, 128, kO); }
        BAR(); MFMA_Q(0, 1); BAR();
        // phase 6
        LOAD_A(As1, 1);
        if (nl) { STG(Bblk, Bs1, 0, kO); STG(Bblk, Bs1, 64, kO); }
        BAR(); MFMA_Q(1, 0); BAR();
        // phase 7
        if (nl) { STG(Ablk, As1, 64, kO); STG(Ablk, As1, 192, kO); }
        BAR(); MFMA_Q(1, 1);
        if (nl) { VMC6(); }                    // buf0 (K-tile 2it+2) ready
        BAR();
    }

    if (MODE == 0) {
        bf16* ob = (bf16*)out;
        #pragma unroll
        for (int f = 0; f < 8; f++) {
            int row0 = m0 + wm128 + f * 16 + quad * 4;
            #pragma unroll
            for (int g = 0; g < 4; g++) {
                int n = n0 + wn64 + g * 16 + lm;
                float bsn = bias[n];
                #pragma unroll
                for (int r = 0; r < 4; r++)
                    ob[(size_t)(row0 + r) * N + n] = (bf16)(acc[f][g][r] + bsn);
            }
        }
    } else {
        // row-major out via per-wave 64x68 patch (vectorized 16B stores)
        bf16* ob = (bf16*)out;
        bf16* patch = smem + wid * (64 * 68);
        #pragma unroll
        for (int h = 0; h < 2; h++) {
            #pragma unroll
            for (int ff = 0; ff < 4; ff++)
                #pragma unroll
                for (int g = 0; g < 4; g++) {
                    int n = n0 + wn64 + g * 16 + lm;
                    float bsn = bias[n];
                    #pragma unroll
                    for (int r = 0; r < 4; r++)
                        patch[(ff * 16 + quad * 4 + r) * 68 + g * 16 + lm] =
                            (bf16)gelu_fast(acc[h * 4 + ff][g][r] + bsn);
                }
            #pragma unroll
            for (int ff = 0; ff < 4; ff++)
                #pragma unroll
                for (int kc = 0; kc < 2; kc++) {
                    bf16x8 v = *(const bf16x8*)&patch[(ff * 16 + lm) * 68 + kc * 32 + quad * 8];
                    size_t row = (size_t)(m0 + wm128 + h * 64 + ff * 16 + lm);
                    *(bf16x8*)(ob + row * N + n0 + wn64 + kc * 32 + quad * 8) = v;
                }
        }
    }
}

// ---------------------------------------------------------------------------
// Narrow-N pipelined GEMM: 128x128 tile, 8 waves (4M x 2N, wave = 32x64),
// BK=64, FOUR LDS stage buffers (128 KB) = 3-tiles-ahead counted-vmcnt
// pipeline. One raw s_barrier per K-tile; vmcnt never drained to 0 until the
// tail. A row-major [M][K] bf16, B row-major [N][K] bf16.
// out f32 = acc + bias[n] + add[idx]. Grid 256 blocks (M/128 x N/128),
// XCD-grouped so each XCD owns 4 consecutive m-panels.
// Schedule invariant at end of iter t: tiles <= t+1 landed; t+2,t+3 in
// flight (8 outstanding gload_lds per wave). Iter t stages tile t+3 into
// buf[(t+3)&3] = buf[(t-1)&3], whose readers all passed barrier B_{t-1}.
// ---------------------------------------------------------------------------
#define VMCP(n) asm volatile("s_waitcnt vmcnt(" #n ")" ::: "memory")

#define STGP(kt) { bf16* bs_ = smem + ((kt) & 3) * 16384; \
    gload_lds16(Ab + (size_t)sr8 * K + (kt) * 64 + scb,        bs_ + (wid * 8) * 64); \
    gload_lds16(Ab + (size_t)(64 + sr8) * K + (kt) * 64 + scb, bs_ + (64 + wid * 8) * 64); \
    gload_lds16(Bb + (size_t)sr8 * K + (kt) * 64 + scb,        bs_ + 8192 + (wid * 8) * 64); \
    gload_lds16(Bb + (size_t)(64 + sr8) * K + (kt) * 64 + scb, bs_ + 8192 + (64 + wid * 8) * 64); }

__global__ __launch_bounds__(512, 2) void gemm_npipe(const bf16* __restrict__ A,
                                                     const bf16* __restrict__ Bt,
                                                     const float* __restrict__ bias,
                                                     const float* __restrict__ add,
                                                     float* __restrict__ out,
                                                     int N, int K) {
    __shared__ __align__(16) bf16 smem[4 * 16384];   // 4 bufs x (A 8K + B 8K elems)
    int lin = blockIdx.x;
    int xcd = lin & 7, loc = lin >> 3;               // loc 0..31
    int m0 = (xcd * 4 + (loc & 3)) * 128;
    int n0 = (loc >> 2) * 128;
    int tid = threadIdx.x;
    int wid = __builtin_amdgcn_readfirstlane(tid >> 6);
    int lane = tid & 63;
    int lm = lane & 15, quad = lane >> 4;
    int wm32 = (wid & 3) * 32, wn64 = (wid >> 2) * 64;
    int sr8 = wid * 8 + (lane >> 3);
    int scb = ((lane & 7) ^ (lane >> 3)) << 3;
    const bf16* Ab = A  + (size_t)m0 * K;
    const bf16* Bb = Bt + (size_t)n0 * K;
    int NT = K >> 6;

    floatx4 acc[2][4];
    #pragma unroll
    for (int i = 0; i < 2; i++)
        #pragma unroll
        for (int j = 0; j < 4; j++) { floatx4 z = {0.f, 0.f, 0.f, 0.f}; acc[i][j] = z; }
    bf16x8 aR[2][2], bR[4][2];

    STGP(0); STGP(1); STGP(2);
    VMCP(8);          // tile 0 landed; tiles 1,2 (8 issues) in flight
    BAR();

    for (int t = 0; t < NT; t++) {
        if (t + 3 < NT) STGP(t + 3);
        bf16* bs = smem + (t & 3) * 16384;
        #pragma unroll
        for (int i = 0; i < 2; i++)
            #pragma unroll
            for (int kc = 0; kc < 2; kc++)
                aR[i][kc] = *(const bf16x8*)(bs + (wm32 + i * 16 + lm) * 64 +
                                             ((((kc << 2) | quad) ^ (lm & 7)) << 3));
        #pragma unroll
        for (int j = 0; j < 4; j++)
            #pragma unroll
            for (int kc = 0; kc < 2; kc++)
                bR[j][kc] = *(const bf16x8*)(bs + 8192 + (wn64 + j * 16 + lm) * 64 +
                                             ((((kc << 2) | quad) ^ (lm & 7)) << 3));
        __builtin_amdgcn_s_setprio(1);
        #pragma unroll
        for (int kc = 0; kc < 2; kc++)
            #pragma unroll
            for (int i = 0; i < 2; i++)
                #pragma unroll
                for (int j = 0; j < 4; j++)
                    acc[i][j] = __builtin_amdgcn_mfma_f32_16x16x32_bf16(
                        aR[i][kc], bR[j][kc], acc[i][j], 0, 0, 0);
        __builtin_amdgcn_s_setprio(0);
        if (t + 3 < NT)      { VMCP(8); }   // tile t+1 landed; t+2,t+3 in flight
        else if (t == NT - 3){ VMCP(4); }   // tile NT-2 landed
        else if (t == NT - 2){ VMCP(0); }   // tile NT-1 landed
        BAR();
    }

    #pragma unroll
    for (int i = 0; i < 2; i++)
        #pragma unroll
        for (int j = 0; j < 4; j++) {
            int mbase = m0 + wm32 + i * 16 + quad * 4;
            int n     = n0 + wn64 + j * 16 + lm;
            float bsn = bias[n];
            #pragma unroll
            for (int r = 0; r < 4; r++) {
                size_t idx = (size_t)(mbase + r) * N + n;
                out[idx] = acc[i][j][r] + bsn + add[idx];
            }
        }
}

// ---------------------------------------------------------------------------
// Flash attention, MFMA, S^T formulation — 8 waves x 16 q-rows (512 thr).
// Q pre-scaled by 1/sqrt(64); wave-uniform diagonal-tile branch.
// Output ROW-MAJOR bf16 [B*T][C] for gemm_npipe.
// ---------------------------------------------------------------------------
#define QT_ 128
#define KT_ 64

__global__ __launch_bounds__(512) void attn_mfma_kernel(const bf16* __restrict__ qkv,
                                                        bf16* __restrict__ of) {
    int bh = blockIdx.x;
    int b = bh >> 4, h = bh & 15;
    int q0 = (gridDim.y - 1 - blockIdx.y) * QT_;   // heavy-first
    int tid = threadIdx.x, wid = tid >> 6, lane = tid & 63;
    int lm = lane & 15, quad = lane >> 4;
    int sw = lm & 7;
    int r0 = q0 + wid * 16;                        // this wave's 16 q-rows

    const bf16* base = qkv + (size_t)b * T_ * (3 * C_) + h * (3 * HD_);

    __shared__ __align__(16) bf16 Ks[KT_][72];      // K rows [key][d]
    __shared__ __align__(16) bf16 Vt[HD_][72];      // V^T [d][key-swizzled]
    __shared__ __align__(16) bf16 PsT[8][16][64];   // per-wave P [qrow][key-swizzled]

    bf16x8 qf[2];
    #pragma unroll
    for (int kc = 0; kc < 2; kc++) {
        bf16x8 t = *(const bf16x8*)(base + (size_t)(r0 + lm) * (3 * C_) + kc * 32 + quad * 8);
        #pragma unroll
        for (int e = 0; e < 8; e++) t[e] = (bf16)((float)t[e] * 0.125f);
        qf[kc] = t;
    }

    floatx4 acc_o[4];
    #pragma unroll
    for (int dn = 0; dn < 4; dn++) { floatx4 z = {0.f, 0.f, 0.f, 0.f}; acc_o[dn] = z; }
    float mst = -1e30f, lst = 0.0f;

    int srow = tid >> 3;              // 0..63
    int scol = (tid & 7) * 8;

    int kmax = q0 + QT_;
    for (int k0 = 0; k0 < kmax; k0 += KT_) {
        bf16x8 kv = *(const bf16x8*)(base + (size_t)(k0 + srow) * (3 * C_) + HD_ + scol);
        bf16x8 vv = *(const bf16x8*)(base + (size_t)(k0 + srow) * (3 * C_) + 2 * HD_ + scol);
        __syncthreads();
        *(bf16x8*)(&Ks[srow][scol]) = kv;
        {
            int c = scol >> 3;
            int pk = ((srow >> 3) ^ c) * 8 + (srow & 7);
            #pragma unroll
            for (int j = 0; j < 8; j++) Vt[scol + j][pk] = vv[j];
        }
        __syncthreads();

        if (k0 <= r0 + 15) {
            floatx4 st[4];
            #pragma unroll
            for (int bn = 0; bn < 4; bn++) { floatx4 z = {0.f, 0.f, 0.f, 0.f}; st[bn] = z; }
            #pragma unroll
            for (int kc = 0; kc < 2; kc++) {
                bf16x8 kf[4];
                #pragma unroll
                for (int bn = 0; bn < 4; bn++)
                    kf[bn] = *(const bf16x8*)(&Ks[bn * 16 + lm][kc * 32 + quad * 8]);
                __builtin_amdgcn_s_setprio(1);
                #pragma unroll
                for (int bn = 0; bn < 4; bn++)
                    st[bn] = __builtin_amdgcn_mfma_f32_16x16x32_bf16(kf[bn], qf[kc], st[bn], 0, 0, 0);
                __builtin_amdgcn_s_setprio(0);
            }

            float vv_[4][4];
            float rm = -1e30f;
            if (k0 + KT_ - 1 > r0) {      // diagonal tile (wave-uniform branch)
                int gq = r0 + lm;
                #pragma unroll
                for (int bn = 0; bn < 4; bn++)
                    #pragma unroll
                    for (int r = 0; r < 4; r++) {
                        int key = k0 + bn * 16 + quad * 4 + r;
                        float sv = (key <= gq) ? st[bn][r] : -1e30f;
                        vv_[bn][r] = sv;
                        rm = fmaxf(rm, sv);
                    }
            } else {
                #pragma unroll
                for (int bn = 0; bn < 4; bn++)
                    #pragma unroll
                    for (int r = 0; r < 4; r++) {
                        vv_[bn][r] = st[bn][r];
                        rm = fmaxf(rm, st[bn][r]);
                    }
            }
            rm = fmaxf(rm, __shfl_xor(rm, 16));
            rm = fmaxf(rm, __shfl_xor(rm, 32));
            float mnew = fmaxf(mst, rm);
            float alpha = __expf(mst - mnew);
            mst = mnew;
            float ps = 0.f;
            #pragma unroll
            for (int bn = 0; bn < 4; bn++) {
                float p0 = __expf(vv_[bn][0] - mnew);
                float p1 = __expf(vv_[bn][1] - mnew);
                float p2 = __expf(vv_[bn][2] - mnew);
                float p3 = __expf(vv_[bn][3] - mnew);
                ps += (p0 + p1) + (p2 + p3);
                bf16x4 pk = { (bf16)p0, (bf16)p1, (bf16)p2, (bf16)p3 };
                int kb = bn * 2 + (quad >> 1);
                int col = ((kb ^ sw) << 3) + (quad & 1) * 4;
                *(bf16x4*)(&PsT[wid][lm][col]) = pk;
            }
            ps += __shfl_xor(ps, 16);
            ps += __shfl_xor(ps, 32);
            lst = lst * alpha + ps;

            #pragma unroll
            for (int r = 0; r < 4; r++) {
                float ar = __shfl(alpha, quad * 4 + r);
                #pragma unroll
                for (int dn = 0; dn < 4; dn++) acc_o[dn][r] *= ar;
            }

            __asm__ volatile("s_waitcnt lgkmcnt(0)" ::: "memory");

            #pragma unroll
            for (int kc = 0; kc < 2; kc++) {
                bf16x8 pa = *(const bf16x8*)(&PsT[wid][lm][((kc * 4 + quad) ^ sw) << 3]);
                bf16x8 vfr[4];
                #pragma unroll
                for (int dn = 0; dn < 4; dn++) {
                    int d = dn * 16 + lm;
                    int swd = (d >> 3) & 7;
                    vfr[dn] = *(const bf16x8*)(&Vt[d][(((kc * 4 + quad) ^ swd) << 3)]);
                }
                __builtin_amdgcn_s_setprio(1);
                #pragma unroll
                for (int dn = 0; dn < 4; dn++)
                    acc_o[dn] = __builtin_amdgcn_mfma_f32_16x16x32_bf16(pa, vfr[dn], acc_o[dn], 0, 0, 0);
                __builtin_amdgcn_s_setprio(0);
            }
        }
    }

    float il = 1.0f / lst;
    #pragma unroll
    for (int r = 0; r < 4; r++) {
        float ir = __shfl(il, quad * 4 + r);
        #pragma unroll
        for (int dn = 0; dn < 4; dn++)
            PsT[wid][quad * 4 + r][dn * 16 + lm] = (bf16)(acc_o[dn][r] * ir);
    }
    __asm__ volatile("s_waitcnt lgkmcnt(0)" ::: "memory");
    size_t rowg = (size_t)b * T_ + r0 + lm;
    #pragma unroll
    for (int kcl = 0; kcl < 2; kcl++) {
        bf16x8 v = *(const bf16x8*)&PsT[wid][lm][kcl * 32 + quad * 8];
        *(bf16x8*)(of + rowg * C_ + h * HD_ + kcl * 32 + quad * 8) = v;
    }
}

// ---------------------------------------------------------------------------
extern "C" void kernel_launch(void* const* d_in, const int* in_sizes, int n_in,
                              void* d_out, int out_size, void* d_ws, size_t ws_size,
                              hipStream_t stream) {
    (void)in_sizes; (void)n_in; (void)out_size; (void)ws_size;
    const float* x      = (const float*)d_in[0];
    const float* ln1_g  = (const float*)d_in[1];
    const float* ln1_b  = (const float*)d_in[2];
    const float* ln2_g  = (const float*)d_in[3];
    const float* ln2_b  = (const float*)d_in[4];
    const float* w_in   = (const float*)d_in[5];
    const float* b_in   = (const float*)d_in[6];
    const float* w_out  = (const float*)d_in[7];
    const float* b_out  = (const float*)d_in[8];
    const float* w_fc   = (const float*)d_in[9];
    const float* b_fc   = (const float*)d_in[10];
    const float* w_proj = (const float*)d_in[11];
    const float* b_proj = (const float*)d_in[12];

    char* ws = (char*)d_ws;
    const size_t MB = 1024 * 1024;
    bf16*  w_inT   = (bf16*)(ws + 0);        // 6 MB row-major (N,K)
    bf16*  w_outT  = (bf16*)(ws + 6 * MB);   // 2 MB row-major (N,K)
    bf16*  w_fcT   = (bf16*)(ws + 8 * MB);   // 8 MB row-major (N,K)
    bf16*  w_projT = (bf16*)(ws + 16 * MB);  // 8 MB row-major (N,K)
    bf16*  qkv     = (bf16*)(ws + 24 * MB);  // 24 MB (shares 32MB region with fc_b)
    bf16*  fc_b    = (bf16*)(ws + 24 * MB);  // 32 MB row-major [4096][4096]
    bf16*  o_b     = (bf16*)(ws + 56 * MB);  // 8 MB row-major (shares with y_b)
    bf16*  y_b     = (bf16*)(ws + 56 * MB);  // 8 MB
    bf16*  h_b     = (bf16*)(ws + 64 * MB);  // 8 MB (shares 16MB region with x1)
    float* x1      = (float*)(ws + 64 * MB); // 16 MB
    float* y_f     = (float*)(ws + 80 * MB); // 16 MB

    const int M = B_ * T_;  // 4096

    transpose_all<<<12288, 256, 0, stream>>>(w_in, w_out, w_fc, w_proj,
                                             w_inT, w_outT, w_fcT, w_projT);

    ln_kernel<<<M, 256, 0, stream>>>(x, ln1_g, ln1_b, h_b, nullptr);
    gemm256<0><<<(M >> 8) * ((3 * C_) >> 8), 512, 0, stream>>>(h_b, w_inT, b_in,
                                                               qkv, M, 3 * C_, C_);
    attn_mfma_kernel<<<dim3(B_ * H_, T_ / QT_), 512, 0, stream>>>(qkv, o_b);
    gemm_npipe<<<256, 512, 0, stream>>>(o_b, w_outT, b_out, x, x1, C_, C_);
    ln_kernel<<<M, 256, 0, stream>>>(x1, ln2_g, ln2_b, y_b, y_f);
    gemm256<1><<<(M >> 8) * ((4 * C_) >> 8), 512, 0, stream>>>(y_b, w_fcT, b_fc,
                                                               fc_b, M, 4 * C_, C_);
    gemm_npipe<<<256, 512, 0, stream>>>(fc_b, w_projT, b_proj, y_f,
                                        (float*)d_out, C_, 4 * C_);
}

// Round 3
// 314.721 us; speedup vs baseline: 1.1150x; 1.0156x over previous
//
#include <hip/hip_runtime.h>
#include <hip/hip_bf16.h>
#include <math.h>

typedef __bf16 bf16;
typedef __bf16 bf16x8 __attribute__((ext_vector_type(8)));
typedef __bf16 bf16x4 __attribute__((ext_vector_type(4)));
typedef float floatx4 __attribute__((ext_vector_type(4)));
typedef int intx4 __attribute__((ext_vector_type(4)));

#define B_ 2
#define T_ 2048
#define C_ 1024
#define H_ 16
#define HD_ 64

// async global->LDS, 16B per lane; lds dest = uniform base + lane*16
__device__ __forceinline__ void gload_lds16(const bf16* g, bf16* l) {
    __builtin_amdgcn_global_load_lds(
        (const __attribute__((address_space(1))) unsigned int*)(g),
        (__attribute__((address_space(3))) unsigned int*)(l), 16, 0, 0);
}

// ---------------------------------------------------------------------------
// Weight preprocessing: all four weights (K,N) f32 -> (N,K) bf16 row-major.
// 32x32 tiles, 256 threads (32x8).
// ---------------------------------------------------------------------------
__global__ __launch_bounds__(256) void transpose_all(
        const float* __restrict__ w_in, const float* __restrict__ w_out,
        const float* __restrict__ w_fc, const float* __restrict__ w_proj,
        bf16* __restrict__ o_in, bf16* __restrict__ o_out,
        bf16* __restrict__ o_fc, bf16* __restrict__ o_proj) {
    __shared__ float shf[32 * 33];
    int t = blockIdx.x;
    int tid = threadIdx.x;
    const float* src; bf16* dst; int K, N, idx;
    if (t < 3072)      { src = w_in;   dst = o_in;   K = 1024; N = 3072; idx = t; }
    else if (t < 7168) { src = w_fc;   dst = o_fc;   K = 1024; N = 4096; idx = t - 3072; }
    else if (t < 8192) { src = w_out;  dst = o_out;  K = 1024; N = 1024; idx = t - 7168; }
    else               { src = w_proj; dst = o_proj; K = 4096; N = 1024; idx = t - 8192; }
    int ntx = N >> 5;
    int nt = (idx % ntx) * 32, kt = (idx / ntx) * 32;
    int tx = tid & 31, ty = tid >> 5;  // 32 x 8
    #pragma unroll
    for (int i = 0; i < 32; i += 8)
        shf[(ty + i) * 33 + tx] = src[(size_t)(kt + ty + i) * N + nt + tx];
    __syncthreads();
    #pragma unroll
    for (int i = 0; i < 32; i += 8)
        dst[(size_t)(nt + ty + i) * K + kt + tx] = (bf16)shf[tx * 33 + ty + i];
}

// ---------------------------------------------------------------------------
// LayerNorm over C=1024. One block (256 threads) per row; 4 floats/thread.
// ---------------------------------------------------------------------------
__global__ __launch_bounds__(256) void ln_kernel(const float* __restrict__ x,
                                                 const float* __restrict__ g,
                                                 const float* __restrict__ b,
                                                 bf16* __restrict__ out_b,
                                                 float* __restrict__ out_f) {
    int row = blockIdx.x;
    int tid = threadIdx.x;
    const float* xr = x + (size_t)row * C_;
    float4 v = ((const float4*)xr)[tid];
    float s  = v.x + v.y + v.z + v.w;
    float ss = v.x * v.x + v.y * v.y + v.z * v.z + v.w * v.w;
    #pragma unroll
    for (int off = 32; off; off >>= 1) {
        s  += __shfl_down(s, off);
        ss += __shfl_down(ss, off);
    }
    __shared__ float red[8];
    int wid = tid >> 6;
    if ((tid & 63) == 0) { red[wid] = s; red[wid + 4] = ss; }
    __syncthreads();
    s  = red[0] + red[1] + red[2] + red[3];
    ss = red[4] + red[5] + red[6] + red[7];
    float mean = s * (1.0f / C_);
    float var  = ss * (1.0f / C_) - mean * mean;
    float rstd = rsqrtf(var + 1e-5f);
    float4 gv = ((const float4*)g)[tid];
    float4 bv = ((const float4*)b)[tid];
    float o0 = (v.x - mean) * rstd * gv.x + bv.x;
    float o1 = (v.y - mean) * rstd * gv.y + bv.y;
    float o2 = (v.z - mean) * rstd * gv.z + bv.z;
    float o3 = (v.w - mean) * rstd * gv.w + bv.w;
    bf16x4 ob = { (bf16)o0, (bf16)o1, (bf16)o2, (bf16)o3 };
    ((bf16x4*)out_b)[(size_t)row * 256 + tid] = ob;
    if (out_f) {
        float4 of; of.x = o0; of.y = o1; of.z = o2; of.w = o3;
        ((float4*)out_f)[(size_t)row * 256 + tid] = of;
    }
}

__device__ __forceinline__ float gelu_fast(float x) {
    // tanh-form GELU, |err| vs exact erf form < ~1e-3 (output slack ~0.10)
    float z2 = 1.5957691216f * (x + 0.044715f * x * x * x);   // 2*0.79788456*(x+..)
    float e = __expf(z2);
    float t = 1.0f - 2.0f * __builtin_amdgcn_rcpf(e + 1.0f);  // tanh(z)
    return 0.5f * x * (1.0f + t);
}

// ---------------------------------------------------------------------------
// 256x256-tile GEMM, 8 waves (2M x 4N), BK=64, 8-phase counted-vmcnt schedule
// (T2+T3+T4+T5). LDS 128 KB = 2 dbuf x (A[256][64] + B[256][64]).
// MODE 0: +bias, bf16 row-major out (qkv).
// MODE 1: +bias+gelu, bf16 ROW-MAJOR out via per-wave 64x68 LDS patches.
// ---------------------------------------------------------------------------
#define BAR() do { __builtin_amdgcn_sched_barrier(0); __builtin_amdgcn_s_barrier(); __builtin_amdgcn_sched_barrier(0); } while (0)
#define VMC6() asm volatile("s_waitcnt vmcnt(6)" ::: "memory")
#define VMC0() asm volatile("s_waitcnt vmcnt(0)" ::: "memory")

#define LOAD_A(AS, QM) \
  { _Pragma("unroll") for (int i_ = 0; i_ < 4; i_++) { \
      const int r_ = wm128 + ((QM) * 4 + i_) * 16 + lm; \
      _Pragma("unroll") for (int kc_ = 0; kc_ < 2; kc_++) \
        aR[i_][kc_] = *(const bf16x8*)((AS) + r_ * 64 + ((((kc_ << 2) | quad) ^ (lm & 7)) << 3)); } }

#define LOAD_B(BS, QN) \
  { _Pragma("unroll") for (int j_ = 0; j_ < 2; j_++) { \
      const int r_ = wn64 + ((QN) * 2 + j_) * 16 + lm; \
      _Pragma("unroll") for (int kc_ = 0; kc_ < 2; kc_++) \
        bR[QN][j_][kc_] = *(const bf16x8*)((BS) + r_ * 64 + ((((kc_ << 2) | quad) ^ (lm & 7)) << 3)); } }

#define MFMA_Q(QM, QN) \
  { __builtin_amdgcn_s_setprio(1); \
    _Pragma("unroll") for (int i_ = 0; i_ < 4; i_++) \
    _Pragma("unroll") for (int j_ = 0; j_ < 2; j_++) \
    _Pragma("unroll") for (int kc_ = 0; kc_ < 2; kc_++) \
      acc[(QM) * 4 + i_][(QN) * 2 + j_] = __builtin_amdgcn_mfma_f32_16x16x32_bf16( \
          aR[i_][kc_], bR[QN][j_][kc_], acc[(QM) * 4 + i_][(QN) * 2 + j_], 0, 0, 0); \
    __builtin_amdgcn_s_setprio(0); }

#define STG(gb, lb, r0v, k0v) \
    gload_lds16((gb) + (size_t)((r0v) + sr8) * K + (k0v) + scb, (lb) + ((r0v) + wid * 8) * 64)

template<int MODE>
__global__ __launch_bounds__(512, 2) void gemm256(const bf16* __restrict__ A,
                                                  const bf16* __restrict__ Bt,
                                                  const float* __restrict__ bias,
                                                  void* __restrict__ out,
                                                  int M, int N, int K) {
    (void)M;
    __shared__ __align__(16) bf16 smem[4 * 256 * 64];   // 128 KB
    bf16* As0 = smem;
    bf16* Bs0 = smem + 1 * 256 * 64;
    bf16* As1 = smem + 2 * 256 * 64;
    bf16* Bs1 = smem + 3 * 256 * 64;

    // XCD-chunked bijective swizzle (gridDim.x % 8 == 0 for all our shapes)
    int ntn = N >> 8;
    int lin = blockIdx.x;
    int id  = (lin & 7) * (gridDim.x >> 3) + (lin >> 3);
    int mt = id / ntn, nt = id - mt * ntn;
    int m0 = mt << 8, n0 = nt << 8;

    int tid = threadIdx.x;
    int wid = __builtin_amdgcn_readfirstlane(tid >> 6);
    int lane = tid & 63;
    int lm = lane & 15, quad = lane >> 4;
    int wm128 = (wid & 1) * 128;     // wave M offset within tile
    int wn64  = (wid >> 1) * 64;     // wave N offset within tile

    const bf16* Ablk = A  + (size_t)m0 * K;
    const bf16* Bblk = Bt + (size_t)n0 * K;

    int sr8 = wid * 8 + (lane >> 3);               // staging row within round
    int scb = ((lane & 7) ^ (lane >> 3)) << 3;     // xor-swizzled source colblock

    floatx4 acc[8][4];
    #pragma unroll
    for (int f = 0; f < 8; f++)
        #pragma unroll
        for (int g = 0; g < 4; g++) { floatx4 z = {0.f, 0.f, 0.f, 0.f}; acc[f][g] = z; }
    bf16x8 aR[4][2], bR[2][2][2];

    int nI = K >> 7;   // iterations; 2 K-tiles (BK=64) each

    // prologue: K-tile 0 full (8 loads, oldest), K-tile 1 minus B rows128-255
    STG(Ablk, As0, 0, 0);   STG(Ablk, As0, 64, 0);
    STG(Ablk, As0, 128, 0); STG(Ablk, As0, 192, 0);
    STG(Bblk, Bs0, 0, 0);   STG(Bblk, Bs0, 64, 0);
    STG(Bblk, Bs0, 128, 0); STG(Bblk, Bs0, 192, 0);
    STG(Ablk, As1, 0, 64);  STG(Ablk, As1, 128, 64);
    STG(Bblk, Bs1, 0, 64);  STG(Bblk, Bs1, 64, 64);
    STG(Ablk, As1, 64, 64); STG(Ablk, As1, 192, 64);
    VMC6();                 // K-tile 0 landed; <=6 (K-tile 1 partial) in flight
    BAR();

    for (int it = 0; it < nI; it++) {
        int kE = (2 * it + 2) << 6;
        int kO = (2 * it + 3) << 6;
        int kT = (2 * it + 1) << 6;
        bool nl = (it + 1 < nI);
        // phase 0
        LOAD_A(As0, 0); LOAD_B(Bs0, 0);
        STG(Bblk, Bs1, 128, kT); STG(Bblk, Bs1, 192, kT);
        BAR(); MFMA_Q(0, 0); BAR();
        // phase 1
        LOAD_B(Bs0, 1);
        if (nl) { STG(Ablk, As0, 0, kE); STG(Ablk, As0, 128, kE); }
        BAR(); MFMA_Q(0, 1); BAR();
        // phase 2
        LOAD_A(As0, 1);
        if (nl) { STG(Bblk, Bs0, 0, kE); STG(Bblk, Bs0, 64, kE); }
        BAR(); MFMA_Q(1, 0); BAR();
        // phase 3
        if (nl) { STG(Ablk, As0, 64, kE); STG(Ablk, As0, 192, kE); }
        BAR(); MFMA_Q(1, 1);
        if (nl) { VMC6(); } else { VMC0(); }   // buf1 (K-tile 2it+1) ready
        BAR();
        // phase 4
        LOAD_A(As1, 0); LOAD_B(Bs1, 0);
        if (nl) { STG(Bblk, Bs0, 128, kE); STG(Bblk, Bs0, 192, kE); }
        BAR(); MFMA_Q(0, 0); BAR();
        // phase 5
        LOAD_B(Bs1, 1);
        if (nl) { STG(Ablk, As1, 0, kO); STG(Ablk, As1, 128, kO); }
        BAR(); MFMA_Q(0, 1); BAR();
        // phase 6
        LOAD_A(As1, 1);
        if (nl) { STG(Bblk, Bs1, 0, kO); STG(Bblk, Bs1, 64, kO); }
        BAR(); MFMA_Q(1, 0); BAR();
        // phase 7
        if (nl) { STG(Ablk, As1, 64, kO); STG(Ablk, As1, 192, kO); }
        BAR(); MFMA_Q(1, 1);
        if (nl) { VMC6(); }                    // buf0 (K-tile 2it+2) ready
        BAR();
    }

    if (MODE == 0) {
        bf16* ob = (bf16*)out;
        #pragma unroll
        for (int f = 0; f < 8; f++) {
            int row0 = m0 + wm128 + f * 16 + quad * 4;
            #pragma unroll
            for (int g = 0; g < 4; g++) {
                int n = n0 + wn64 + g * 16 + lm;
                float bsn = bias[n];
                #pragma unroll
                for (int r = 0; r < 4; r++)
                    ob[(size_t)(row0 + r) * N + n] = (bf16)(acc[f][g][r] + bsn);
            }
        }
    } else {
        // row-major out via per-wave 64x68 patch (vectorized 16B stores)
        bf16* ob = (bf16*)out;
        bf16* patch = smem + wid * (64 * 68);
        #pragma unroll
        for (int h = 0; h < 2; h++) {
            #pragma unroll
            for (int ff = 0; ff < 4; ff++)
                #pragma unroll
                for (int g = 0; g < 4; g++) {
                    int n = n0 + wn64 + g * 16 + lm;
                    float bsn = bias[n];
                    #pragma unroll
                    for (int r = 0; r < 4; r++)
                        patch[(ff * 16 + quad * 4 + r) * 68 + g * 16 + lm] =
                            (bf16)gelu_fast(acc[h * 4 + ff][g][r] + bsn);
                }
            #pragma unroll
            for (int ff = 0; ff < 4; ff++)
                #pragma unroll
                for (int kc = 0; kc < 2; kc++) {
                    bf16x8 v = *(const bf16x8*)&patch[(ff * 16 + lm) * 68 + kc * 32 + quad * 8];
                    size_t row = (size_t)(m0 + wm128 + h * 64 + ff * 16 + lm);
                    *(bf16x8*)(ob + row * N + n0 + wn64 + kc * 32 + quad * 8) = v;
                }
        }
    }
}

// ---------------------------------------------------------------------------
// Narrow-N pipelined GEMM: 128x128 tile, 8 waves (4M x 2N, wave = 32x64),
// BK=64, FOUR LDS stage buffers (128 KB) = 3-tiles-ahead counted-vmcnt
// pipeline. One raw s_barrier per K-tile; vmcnt never drained to 0 until the
// tail. A row-major [M][K] bf16, B row-major [N][K] bf16.
// ---------------------------------------------------------------------------
#define VMCP(n) asm volatile("s_waitcnt vmcnt(" #n ")" ::: "memory")

#define STGP(kt) { bf16* bs_ = smem + ((kt) & 3) * 16384; \
    gload_lds16(Ab + (size_t)sr8 * K + (kt) * 64 + scb,        bs_ + (wid * 8) * 64); \
    gload_lds16(Ab + (size_t)(64 + sr8) * K + (kt) * 64 + scb, bs_ + (64 + wid * 8) * 64); \
    gload_lds16(Bb + (size_t)sr8 * K + (kt) * 64 + scb,        bs_ + 8192 + (wid * 8) * 64); \
    gload_lds16(Bb + (size_t)(64 + sr8) * K + (kt) * 64 + scb, bs_ + 8192 + (64 + wid * 8) * 64); }

__global__ __launch_bounds__(512, 2) void gemm_npipe(const bf16* __restrict__ A,
                                                     const bf16* __restrict__ Bt,
                                                     const float* __restrict__ bias,
                                                     const float* __restrict__ add,
                                                     float* __restrict__ out,
                                                     int N, int K) {
    __shared__ __align__(16) bf16 smem[4 * 16384];   // 4 bufs x (A 8K + B 8K elems)
    int lin = blockIdx.x;
    int xcd = lin & 7, loc = lin >> 3;               // loc 0..31
    int m0 = (xcd * 4 + (loc & 3)) * 128;
    int n0 = (loc >> 2) * 128;
    int tid = threadIdx.x;
    int wid = __builtin_amdgcn_readfirstlane(tid >> 6);
    int lane = tid & 63;
    int lm = lane & 15, quad = lane >> 4;
    int wm32 = (wid & 3) * 32, wn64 = (wid >> 2) * 64;
    int sr8 = wid * 8 + (lane >> 3);
    int scb = ((lane & 7) ^ (lane >> 3)) << 3;
    const bf16* Ab = A  + (size_t)m0 * K;
    const bf16* Bb = Bt + (size_t)n0 * K;
    int NT = K >> 6;

    floatx4 acc[2][4];
    #pragma unroll
    for (int i = 0; i < 2; i++)
        #pragma unroll
        for (int j = 0; j < 4; j++) { floatx4 z = {0.f, 0.f, 0.f, 0.f}; acc[i][j] = z; }
    bf16x8 aR[2][2], bR[4][2];

    STGP(0); STGP(1); STGP(2);
    VMCP(8);          // tile 0 landed; tiles 1,2 (8 issues) in flight
    BAR();

    for (int t = 0; t < NT; t++) {
        if (t + 3 < NT) STGP(t + 3);
        bf16* bs = smem + (t & 3) * 16384;
        #pragma unroll
        for (int i = 0; i < 2; i++)
            #pragma unroll
            for (int kc = 0; kc < 2; kc++)
                aR[i][kc] = *(const bf16x8*)(bs + (wm32 + i * 16 + lm) * 64 +
                                             ((((kc << 2) | quad) ^ (lm & 7)) << 3));
        #pragma unroll
        for (int j = 0; j < 4; j++)
            #pragma unroll
            for (int kc = 0; kc < 2; kc++)
                bR[j][kc] = *(const bf16x8*)(bs + 8192 + (wn64 + j * 16 + lm) * 64 +
                                             ((((kc << 2) | quad) ^ (lm & 7)) << 3));
        __builtin_amdgcn_s_setprio(1);
        #pragma unroll
        for (int kc = 0; kc < 2; kc++)
            #pragma unroll
            for (int i = 0; i < 2; i++)
                #pragma unroll
                for (int j = 0; j < 4; j++)
                    acc[i][j] = __builtin_amdgcn_mfma_f32_16x16x32_bf16(
                        aR[i][kc], bR[j][kc], acc[i][j], 0, 0, 0);
        __builtin_amdgcn_s_setprio(0);
        if (t + 3 < NT)      { VMCP(8); }   // tile t+1 landed; t+2,t+3 in flight
        else if (t == NT - 3){ VMCP(4); }   // tile NT-2 landed
        else if (t == NT - 2){ VMCP(0); }   // tile NT-1 landed
        BAR();
    }

    #pragma unroll
    for (int i = 0; i < 2; i++)
        #pragma unroll
        for (int j = 0; j < 4; j++) {
            int mbase = m0 + wm32 + i * 16 + quad * 4;
            int n     = n0 + wn64 + j * 16 + lm;
            float bsn = bias[n];
            #pragma unroll
            for (int r = 0; r < 4; r++) {
                size_t idx = (size_t)(mbase + r) * N + n;
                out[idx] = acc[i][j][r] + bsn + add[idx];
            }
        }
}

// ---------------------------------------------------------------------------
// Flash attention, MFMA, S^T formulation — 8 waves x 16 q-rows (512 thr).
// Round-3 pipeline: double-buffered K/V LDS, K staged direct via
// global_load_lds (XOR-swizzled source cols), V transposed in-register via
// lane-pair shfl + full-dword b32 writes (conflict-free), ONE barrier/tile,
// balanced q-tile remap so each CU's block pair sums to ~constant work.
// Output ROW-MAJOR bf16 [B*T][C].
// ---------------------------------------------------------------------------
#define QT_ 128
#define KT_ 64

// V^T staging: pair (lane, lane^8) holds keys (srow&~1, srow|1) for the same
// 8 d-values. Exchange via 4 shfl_xor, pack bf16x2 per d, write b32.
// Even-srow lane writes d = scol..scol+3, odd writes scol+4..scol+7.
// Bank check: bank = (4*(w^c') + s>>1 + 16*(s&1) + 4j) mod 32 -> exactly 2
// lanes per bank at distinct dwords (free).
__device__ __forceinline__ void vt_stage(bf16* VtB, bf16x8 vv, int vdb,
                                         int vcolb, int oddf) {
    intx4 vi = *(intx4*)&vv;
    intx4 pi;
    #pragma unroll
    for (int m = 0; m < 4; m++) pi[m] = __shfl_xor(vi[m], 8);
    #pragma unroll
    for (int j = 0; j < 4; j++) {
        int w0 = j >> 1, sh = (j & 1) * 16;
        unsigned int oe = ((unsigned int)vi[w0] >> sh) & 0xffffu;
        unsigned int pe = ((unsigned int)pi[w0] >> sh) & 0xffffu;
        unsigned int oo = ((unsigned int)vi[2 + w0] >> sh) & 0xffffu;
        unsigned int po = ((unsigned int)pi[2 + w0] >> sh) & 0xffffu;
        unsigned int de = oe | (pe << 16);          // (even key, odd key)
        unsigned int dn = po | (oo << 16);
        unsigned int dw = oddf ? dn : de;
        *(unsigned int*)(VtB + (size_t)(vdb + j) * 72 + vcolb) = dw;
    }
}

__global__ __launch_bounds__(512) void attn_mfma_kernel(const bf16* __restrict__ qkv,
                                                        bf16* __restrict__ of) {
    int bh = blockIdx.x;
    int b = bh >> 4, h = bh & 15;
    // balanced remap: y<8 -> heavy tiles desc (32-2y), y>=8 -> light asc
    // (2+2(y-8)); dispatch pairs (c, 256+c) then sum to 34 k-tile steps.
    int ny = gridDim.y;                       // 16
    int gy = blockIdx.y;
    int yy = (gy < (ny >> 1)) ? gy : (ny + (ny >> 1) - 1 - gy);
    int q0 = (ny - 1 - yy) * QT_;
    int tid = threadIdx.x;
    int wid = __builtin_amdgcn_readfirstlane(tid >> 6);
    int lane = tid & 63;
    int lm = lane & 15, quad = lane >> 4;
    int sw = lm & 7;
    int r0 = q0 + wid * 16;                   // this wave's 16 q-rows

    const bf16* base = qkv + (size_t)b * T_ * (3 * C_) + h * (3 * HD_);

    __shared__ __align__(16) bf16 Ks[2][KT_][64];   // K, col-block XOR-swizzled
    __shared__ __align__(16) bf16 Vt[2][HD_][72];   // V^T [d][key-blk swizzled]
    __shared__ __align__(16) bf16 PsT[8][16][64];   // per-wave P

    bf16x8 qf[2];
    #pragma unroll
    for (int kc = 0; kc < 2; kc++) {
        bf16x8 t = *(const bf16x8*)(base + (size_t)(r0 + lm) * (3 * C_) + kc * 32 + quad * 8);
        #pragma unroll
        for (int e = 0; e < 8; e++) t[e] = (bf16)((float)t[e] * 0.125f);
        qf[kc] = t;
    }

    floatx4 acc_o[4];
    #pragma unroll
    for (int dn = 0; dn < 4; dn++) { floatx4 z = {0.f, 0.f, 0.f, 0.f}; acc_o[dn] = z; }
    float mst = -1e30f, lst = 0.0f;

    int srow = tid >> 3;                          // 0..63 key row
    int scb  = ((lane & 7) ^ (lane >> 3)) << 3;   // K stage swizzled source col
    int scol = (tid & 7) * 8;                     // V d-block
    int oddf = srow & 1;
    int vcolb = (((srow >> 3) ^ (tid & 7)) << 3) + (srow & 6);
    int vdb   = scol + (oddf ? 4 : 0);

    int ntiles = q0 / KT_ + 2;

    // prologue: stage tile 0 -> buf 0
    {
        gload_lds16(base + (size_t)srow * (3 * C_) + HD_ + scb, &Ks[0][wid * 8][0]);
        bf16x8 vv = *(const bf16x8*)(base + (size_t)srow * (3 * C_) + 2 * HD_ + scol);
        vt_stage(&Vt[0][0][0], vv, vdb, vcolb, oddf);
        __syncthreads();   // drains vmcnt (gload_lds) + lgkm
    }

    for (int t = 0; t < ntiles; t++) {
        int cur = t & 1;
        bool pre = (t + 1 < ntiles);
        bf16x8 vv;
        if (pre) {
            size_t nrow = (size_t)((t + 1) * KT_ + srow) * (3 * C_);
            gload_lds16(base + nrow + HD_ + scb, &Ks[cur ^ 1][wid * 8][0]);
            vv = *(const bf16x8*)(base + nrow + 2 * HD_ + scol);
        }
        __builtin_amdgcn_sched_barrier(0);   // keep prefetch issue above compute

        int k0 = t * KT_;
        if (k0 <= r0 + 15) {                 // wave-uniform causal skip
            floatx4 st[4];
            #pragma unroll
            for (int bn = 0; bn < 4; bn++) { floatx4 z = {0.f, 0.f, 0.f, 0.f}; st[bn] = z; }
            #pragma unroll
            for (int kc = 0; kc < 2; kc++) {
                bf16x8 kf[4];
                #pragma unroll
                for (int bn = 0; bn < 4; bn++)
                    kf[bn] = *(const bf16x8*)(&Ks[cur][bn * 16 + lm]
                                              [((((kc << 2) | quad) ^ sw) << 3)]);
                __builtin_amdgcn_s_setprio(1);
                #pragma unroll
                for (int bn = 0; bn < 4; bn++)
                    st[bn] = __builtin_amdgcn_mfma_f32_16x16x32_bf16(kf[bn], qf[kc], st[bn], 0, 0, 0);
                __builtin_amdgcn_s_setprio(0);
            }

            float vv_[4][4];
            float rm = -1e30f;
            if (k0 + KT_ - 1 > r0) {      // diagonal tile (wave-uniform branch)
                int gq = r0 + lm;
                #pragma unroll
                for (int bn = 0; bn < 4; bn++)
                    #pragma unroll
                    for (int r = 0; r < 4; r++) {
                        int key = k0 + bn * 16 + quad * 4 + r;
                        float sv = (key <= gq) ? st[bn][r] : -1e30f;
                        vv_[bn][r] = sv;
                        rm = fmaxf(rm, sv);
                    }
            } else {
                #pragma unroll
                for (int bn = 0; bn < 4; bn++)
                    #pragma unroll
                    for (int r = 0; r < 4; r++) {
                        vv_[bn][r] = st[bn][r];
                        rm = fmaxf(rm, st[bn][r]);
                    }
            }
            rm = fmaxf(rm, __shfl_xor(rm, 16));
            rm = fmaxf(rm, __shfl_xor(rm, 32));
            float mnew = fmaxf(mst, rm);
            float alpha = __expf(mst - mnew);
            mst = mnew;
            float ps = 0.f;
            #pragma unroll
            for (int bn = 0; bn < 4; bn++) {
                float p0 = __expf(vv_[bn][0] - mnew);
                float p1 = __expf(vv_[bn][1] - mnew);
                float p2 = __expf(vv_[bn][2] - mnew);
                float p3 = __expf(vv_[bn][3] - mnew);
                ps += (p0 + p1) + (p2 + p3);
                bf16x4 pk = { (bf16)p0, (bf16)p1, (bf16)p2, (bf16)p3 };
                int kb = bn * 2 + (quad >> 1);
                int col = ((kb ^ sw) << 3) + (quad & 1) * 4;
                *(bf16x4*)(&PsT[wid][lm][col]) = pk;
            }
            ps += __shfl_xor(ps, 16);
            ps += __shfl_xor(ps, 32);
            lst = lst * alpha + ps;

            #pragma unroll
            for (int r = 0; r < 4; r++) {
                float ar = __shfl(alpha, quad * 4 + r);
                #pragma unroll
                for (int dn = 0; dn < 4; dn++) acc_o[dn][r] *= ar;
            }

            __asm__ volatile("s_waitcnt lgkmcnt(0)" ::: "memory");

            #pragma unroll
            for (int kc = 0; kc < 2; kc++) {
                bf16x8 pa = *(const bf16x8*)(&PsT[wid][lm][((kc * 4 + quad) ^ sw) << 3]);
                bf16x8 vfr[4];
                #pragma unroll
                for (int dn = 0; dn < 4; dn++) {
                    int d = dn * 16 + lm;
                    int swd = (d >> 3) & 7;
                    vfr[dn] = *(const bf16x8*)(&Vt[cur][d][(((kc * 4 + quad) ^ swd) << 3)]);
                }
                __builtin_amdgcn_s_setprio(1);
                #pragma unroll
                for (int dn = 0; dn < 4; dn++)
                    acc_o[dn] = __builtin_amdgcn_mfma_f32_16x16x32_bf16(pa, vfr[dn], acc_o[dn], 0, 0, 0);
                __builtin_amdgcn_s_setprio(0);
            }
        }

        if (pre) vt_stage(&Vt[cur ^ 1][0][0], vv, vdb, vcolb, oddf);
        __syncthreads();   // tile t+1 (K via gload_lds, V via ds_write) ready
    }

    float il = 1.0f / lst;
    #pragma unroll
    for (int r = 0; r < 4; r++) {
        float ir = __shfl(il, quad * 4 + r);
        #pragma unroll
        for (int dn = 0; dn < 4; dn++)
            PsT[wid][quad * 4 + r][dn * 16 + lm] = (bf16)(acc_o[dn][r] * ir);
    }
    __asm__ volatile("s_waitcnt lgkmcnt(0)" ::: "memory");
    size_t rowg = (size_t)b * T_ + r0 + lm;
    #pragma unroll
    for (int kcl = 0; kcl < 2; kcl++) {
        bf16x8 v = *(const bf16x8*)&PsT[wid][lm][kcl * 32 + quad * 8];
        *(bf16x8*)(of + rowg * C_ + h * HD_ + kcl * 32 + quad * 8) = v;
    }
}

// ---------------------------------------------------------------------------
extern "C" void kernel_launch(void* const* d_in, const int* in_sizes, int n_in,
                              void* d_out, int out_size, void* d_ws, size_t ws_size,
                              hipStream_t stream) {
    (void)in_sizes; (void)n_in; (void)out_size; (void)ws_size;
    const float* x      = (const float*)d_in[0];
    const float* ln1_g  = (const float*)d_in[1];
    const float* ln1_b  = (const float*)d_in[2];
    const float* ln2_g  = (const float*)d_in[3];
    const float* ln2_b  = (const float*)d_in[4];
    const float* w_in   = (const float*)d_in[5];
    const float* b_in   = (const float*)d_in[6];
    const float* w_out  = (const float*)d_in[7];
    const float* b_out  = (const float*)d_in[8];
    const float* w_fc   = (const float*)d_in[9];
    const float* b_fc   = (const float*)d_in[10];
    const float* w_proj = (const float*)d_in[11];
    const float* b_proj = (const float*)d_in[12];

    char* ws = (char*)d_ws;
    const size_t MB = 1024 * 1024;
    bf16*  w_inT   = (bf16*)(ws + 0);        // 6 MB row-major (N,K)
    bf16*  w_outT  = (bf16*)(ws + 6 * MB);   // 2 MB row-major (N,K)
    bf16*  w_fcT   = (bf16*)(ws + 8 * MB);   // 8 MB row-major (N,K)
    bf16*  w_projT = (bf16*)(ws + 16 * MB);  // 8 MB row-major (N,K)
    bf16*  qkv     = (bf16*)(ws + 24 * MB);  // 24 MB (shares 32MB region with fc_b)
    bf16*  fc_b    = (bf16*)(ws + 24 * MB);  // 32 MB row-major [4096][4096]
    bf16*  o_b     = (bf16*)(ws + 56 * MB);  // 8 MB row-major (shares with y_b)
    bf16*  y_b     = (bf16*)(ws + 56 * MB);  // 8 MB
    bf16*  h_b     = (bf16*)(ws + 64 * MB);  // 8 MB (shares 16MB region with x1)
    float* x1      = (float*)(ws + 64 * MB); // 16 MB
    float* y_f     = (float*)(ws + 80 * MB); // 16 MB

    const int M = B_ * T_;  // 4096

    transpose_all<<<12288, 256, 0, stream>>>(w_in, w_out, w_fc, w_proj,
                                             w_inT, w_outT, w_fcT, w_projT);

    ln_kernel<<<M, 256, 0, stream>>>(x, ln1_g, ln1_b, h_b, nullptr);
    gemm256<0><<<(M >> 8) * ((3 * C_) >> 8), 512, 0, stream>>>(h_b, w_inT, b_in,
                                                               qkv, M, 3 * C_, C_);
    attn_mfma_kernel<<<dim3(B_ * H_, T_ / QT_), 512, 0, stream>>>(qkv, o_b);
    gemm_npipe<<<256, 512, 0, stream>>>(o_b, w_outT, b_out, x, x1, C_, C_);
    ln_kernel<<<M, 256, 0, stream>>>(x1, ln2_g, ln2_b, y_b, y_f);
    gemm256<1><<<(M >> 8) * ((4 * C_) >> 8), 512, 0, stream>>>(y_b, w_fcT, b_fc,
                                                               fc_b, M, 4 * C_, C_);
    gemm_npipe<<<256, 512, 0, stream>>>(fc_b, w_projT, b_proj, y_f,
                                        (float*)d_out, C_, 4 * C_);
}